// Round 8
// baseline (683.588 us; speedup 1.0000x reference)
//
#include <hip/hip_runtime.h>
#include <stdint.h>

// Problem constants
#define KCOMP 65536
#define DDIM  256
#define ODIM  256
#define BROWS 1024
#define LOG2PI_TERM 235.2482645f   // 0.5 * D * ln(2*pi)

typedef float f32x4 __attribute__((ext_vector_type(4)));
typedef __bf16 bf16x8 __attribute__((ext_vector_type(8)));
typedef unsigned int u32;
typedef unsigned long long u64;
typedef unsigned short u16;

typedef __attribute__((address_space(1))) const u32 gconst_u32;
typedef __attribute__((address_space(3))) u32 lds_u32;

__device__ __forceinline__ u16 f2bf(float f) {
  u32 b = __float_as_uint(f);
  b += 0x7FFFu + ((b >> 16) & 1u);
  return (u16)(b >> 16);
}
__device__ __forceinline__ u32 fkey(float f) {
  u32 b = __float_as_uint(f);
  return b ^ ((b >> 31) ? 0xFFFFFFFFu : 0x80000000u);
}

#define DPP_ROR1 0x121
#define DPP_ROR2 0x122
#define DPP_ROR4 0x124
#define DPP_ROR8 0x128

// ---- ws layouts ----
// BIG path (~69.3 MB): A 1MB | W 64MB | myc 256KB | ckey 4MB
#define WS_A      0u
#define WS_W      (1u << 20)
#define WS_MYC    (65u << 20)
#define WS_KEYB   ((65u << 20) + (1u << 18))
#define WS_NEED_BIG ((size_t)WS_KEYB + (4u << 20))
// SMALL fallback (r7, ~9 MB): A 1MB | ckey 8MB
#define WS_KEYS   (1u << 20)

// 64-lane max reduce on u32 (4 DPP rotations + 2 shfl) — shared by finalizes
#define REDUCE_MAX(m)                                                         \
  {                                                                           \
    u32 o;                                                                    \
    o = (u32)__builtin_amdgcn_mov_dpp((int)m, DPP_ROR1, 0xf, 0xf, false);     \
    m = m > o ? m : o;                                                        \
    o = (u32)__builtin_amdgcn_mov_dpp((int)m, DPP_ROR2, 0xf, 0xf, false);     \
    m = m > o ? m : o;                                                        \
    o = (u32)__builtin_amdgcn_mov_dpp((int)m, DPP_ROR4, 0xf, 0xf, false);     \
    m = m > o ? m : o;                                                        \
    o = (u32)__builtin_amdgcn_mov_dpp((int)m, DPP_ROR8, 0xf, 0xf, false);     \
    m = m > o ? m : o;                                                        \
    o = (u32)__shfl_xor((int)m, 16); m = m > o ? m : o;                       \
    o = (u32)__shfl_xor((int)m, 32); m = m > o ? m : o;                       \
  }

// ---------------------------------------------------------------------------
// Kernel 1: A features. kappa=2d -> x_d^2 ; kappa=2d+1 -> -2 x_d (MFMA A layout).
__global__ void prep_A(const float* __restrict__ x, u16* __restrict__ A) {
  int l = threadIdx.x & 63;
  int wv = threadIdx.x >> 6;
  int t = blockIdx.x;                 // m16 tile 0..63
  int row = t * 16 + (l & 15);
  for (int u = 0; u < 4; ++u) {
    int cc = wv * 4 + u;              // 0..15
    int d0 = cc * 16 + ((l >> 4) << 2);
    float4 xv = *(const float4*)(x + (size_t)row * DDIM + d0);
    float xs[4] = {xv.x, xv.y, xv.z, xv.w};
    uint4 v;
    u32 wds[4];
    for (int e = 0; e < 4; ++e)
      wds[e] = (u32)f2bf(xs[e] * xs[e]) | ((u32)f2bf(-2.0f * xs[e]) << 16);
    v.x = wds[0]; v.y = wds[1]; v.z = wds[2]; v.w = wds[3];
    *(uint4*)(A + ((size_t)(t * 16 + cc) * 64 + l) * 8) = v;
  }
}

// ---------------------------------------------------------------------------
// Kernel 1b (BIG path): W features, frag-linear like A. Per dim, packed u32 =
// f2bf(-0.5*iv) | f2bf(-0.5*miv)<<16, so dot(A,W) = -0.5*quad directly.
// Also per-comp myc = -0.5*sum(m*miv) - sum(log s) - LOG2PI_TERM.
__global__ void prep_W(const float* __restrict__ mean,
                       const float* __restrict__ stdd,
                       u16* __restrict__ W, float* __restrict__ myc) {
  __shared__ float psum[4][16];
  int l = threadIdx.x & 63;
  int wv = threadIdx.x >> 6;
  int t = blockIdx.x;                 // 16-comp tile 0..4095
  int comp = t * 16 + (l & 15);
  float gsum = 0.f;
  for (int u = 0; u < 4; ++u) {
    int cc = wv * 4 + u;              // 0..15
    int d0 = cc * 16 + ((l >> 4) << 2);
    float4 m4 = *(const float4*)(mean + (size_t)comp * DDIM + d0);
    float4 s4 = *(const float4*)(stdd + (size_t)comp * DDIM + d0);
    float ms[4] = {m4.x, m4.y, m4.z, m4.w};
    float ss[4] = {s4.x, s4.y, s4.z, s4.w};
    uint4 v;
    u32 wds[4];
    for (int e = 0; e < 4; ++e) {
      float iv = __builtin_amdgcn_rcpf(ss[e] * ss[e]);
      float miv = ms[e] * iv;
      wds[e] = (u32)f2bf(-0.5f * iv) | ((u32)f2bf(-0.5f * miv) << 16);
      gsum -= 0.5f * ms[e] * miv + __logf(ss[e]);
    }
    v.x = wds[0]; v.y = wds[1]; v.z = wds[2]; v.w = wds[3];
    *(uint4*)(W + ((size_t)(t * 16 + cc) * 64 + l) * 8) = v;
  }
  // lanes l, l+16, l+32, l+48 share comp (l&15): sum the 4 quarter-partials
  gsum += __shfl_xor(gsum, 16);
  gsum += __shfl_xor(gsum, 32);
  if (l < 16) psum[wv][l] = gsum;     // per-wave partial (this wave's 64 dims)
  __syncthreads();
  if (threadIdx.x < 16)
    myc[t * 16 + threadIdx.x] = psum[0][threadIdx.x] + psum[1][threadIdx.x] +
                                psum[2][threadIdx.x] + psum[3][threadIdx.x] -
                                LOG2PI_TERM;
}

// ---------------------------------------------------------------------------
// Kernel 2 (BIG): stream-both GEMM. 7 rounds showed an invariant ~23 CU-cyc
// per MFMA; with W register-resident, every MFMA carries one ds_read_b128
// (12 cyc of the per-CU LDS pipe) and A-reuse (C/16) is VGPR-boxed. Now W is
// streamed from global (precomputed by prep_W) and only the ACC is resident:
// wave = 64 comps x 32 rows, acc 32 VGPR. loads/MFMA: 0.25 LDS (A) + 0.5 L2
// (W, 512KB/block slab, L2-warm). LDS read traffic 4.2GB -> 1.05GB at FULL
// 4 waves/SIMD. Grid 512 = 128 comp-cols x 4 row-splits; 8 stages x 32 rows;
// barrier/ISSUE/MERGE structure verbatim r7. Block emits top-8 per 512 comps.
__global__ __launch_bounds__(512, 4)
void main_gemm_big(const u16* __restrict__ A_ws, const u16* __restrict__ W_ws,
                   const float* __restrict__ myc_ws, u32* __restrict__ ckey) {
  __shared__ __align__(16) char Ash[2][32][1024];   // 64 KB A double-buffer
  __shared__ u32 wsel[2][32][17];      // [buf][row][8 waves x 2 + pad]
  int tid = threadIdx.x, l = tid & 63, w = tid >> 6;   // w = comp-group 0..7
  int nb = blockIdx.x;
  int nbc = nb & 127;                  // comp-col 0..127 (512 comps)
  int rs = nb >> 7;                    // row-split 0..3 (256 rows)
  int p = l & 15, q = l >> 4;

  int Cb = nbc * 512 + w * 64;         // wave's global comp base
  u32 kid0 = (u32)(w * 64 + q * 4);    // local comp id base (9 bits used)
  const u16* Wl = W_ws + (size_t)(Cb >> 4) * 16 * 512 + (size_t)l * 8;

#define ASHP(B, CELL) (&Ash[B][CELL][0])
  // stage S (rows rs*256+S*32, 32 cells of 1 KB) into buf B; wave: 4 cells
#define ISSUE(S, B)                                                           \
  {                                                                           \
    _Pragma("unroll")                                                         \
    for (int u = 0; u < 4; ++u) {                                             \
      int cell = w * 4 + u;                                                   \
      const u16* gsrc = A_ws +                                                \
        ((size_t)((rs * 16 + (S) * 2 + (cell >> 4)) * 16) + (cell & 15)) * 512\
        + (size_t)l * 8;                                                      \
      __builtin_amdgcn_global_load_lds((gconst_u32*)gsrc,                     \
          (lds_u32*)ASHP(B, cell), 16, 0, 0);                                 \
    }                                                                         \
  }

  // merge 16 wsel keys (min = best) -> 8 smallest for 32 rows; emit inverted
#define MERGE_EMIT(ST, B)                                                     \
  {                                                                           \
    int r = tid;                                                              \
    u32 top[8] = {~0u, ~0u, ~0u, ~0u, ~0u, ~0u, ~0u, ~0u};                    \
    _Pragma("unroll")                                                         \
    for (int j = 0; j < 16; ++j) {                                            \
      u32 key = wsel[B][r][j];                                                \
      if (key < top[7]) {                                                     \
        top[7] = key;                                                         \
        for (int z = 7; z > 0 && top[z] < top[z - 1]; --z) {                  \
          u32 tt = top[z]; top[z] = top[z - 1]; top[z - 1] = tt;              \
        }                                                                     \
      }                                                                       \
    }                                                                         \
    int rowg = rs * 256 + (ST) * 32 + r;                                      \
    size_t base = ((size_t)rowg * 128 + nbc) * 8;                             \
    uint4 o1; o1.x = ~top[0]; o1.y = ~top[1]; o1.z = ~top[2]; o1.w = ~top[3]; \
    uint4 o2; o2.x = ~top[4]; o2.y = ~top[5]; o2.z = ~top[6]; o2.w = ~top[7]; \
    *(uint4*)&ckey[base] = o1;                                                \
    *(uint4*)&ckey[base + 4] = o2;                                            \
  }

  ISSUE(0, 0)
  for (int s = 0; s < 8; ++s) {
    int pb = s & 1;
    __syncthreads();                   // buf pb staged; wsel[pb^1] complete
    if (s < 7) ISSUE(s + 1, pb ^ 1)
    if (s > 0 && tid < 32) MERGE_EMIT(s - 1, pb ^ 1)

    // acc[rt][ct]: rows rt*16+p, comps ct*16+q*4+i ; init = myc (reload, L1)
    f32x4 acc[2][4];
#pragma unroll
    for (int ct = 0; ct < 4; ++ct) {
      f32x4 mv = *(const f32x4*)(myc_ws + Cb + ct * 16 + q * 4);
      acc[0][ct] = mv;
      acc[1][ct] = mv;
    }
    __builtin_amdgcn_s_setprio(1);
#pragma unroll
    for (int cc = 0; cc < 16; ++cc) {
      bf16x8 a0 = *(const bf16x8*)(ASHP(pb, cc) + (size_t)l * 16);
      bf16x8 a1 = *(const bf16x8*)(ASHP(pb, 16 + cc) + (size_t)l * 16);
      bf16x8 w0 = *(const bf16x8*)(Wl + (size_t)(0 * 16 + cc) * 512);
      bf16x8 w1 = *(const bf16x8*)(Wl + (size_t)(1 * 16 + cc) * 512);
      bf16x8 w2 = *(const bf16x8*)(Wl + (size_t)(2 * 16 + cc) * 512);
      bf16x8 w3 = *(const bf16x8*)(Wl + (size_t)(3 * 16 + cc) * 512);
      acc[0][0] = __builtin_amdgcn_mfma_f32_16x16x32_bf16(w0, a0, acc[0][0], 0, 0, 0);
      acc[1][0] = __builtin_amdgcn_mfma_f32_16x16x32_bf16(w0, a1, acc[1][0], 0, 0, 0);
      acc[0][1] = __builtin_amdgcn_mfma_f32_16x16x32_bf16(w1, a0, acc[0][1], 0, 0, 0);
      acc[1][1] = __builtin_amdgcn_mfma_f32_16x16x32_bf16(w1, a1, acc[1][1], 0, 0, 0);
      acc[0][2] = __builtin_amdgcn_mfma_f32_16x16x32_bf16(w2, a0, acc[0][2], 0, 0, 0);
      acc[1][2] = __builtin_amdgcn_mfma_f32_16x16x32_bf16(w2, a1, acc[1][2], 0, 0, 0);
      acc[0][3] = __builtin_amdgcn_mfma_f32_16x16x32_bf16(w3, a0, acc[0][3], 0, 0, 0);
      acc[1][3] = __builtin_amdgcn_mfma_f32_16x16x32_bf16(w3, a1, acc[1][3], 0, 0, 0);
    }
    __builtin_amdgcn_s_setprio(0);

    // selection: per rt, lane holds 16 comps (4 ct x 4 i) of x-row rt*16+p.
    // scores all <= -235 < 0: raw-bit unsigned MIN = best.
#define UMIN(a, b) ((a) < (b) ? (a) : (b))
#define UMAX(a, b) ((a) < (b) ? (b) : (a))
#pragma unroll
    for (int rt = 0; rt < 2; ++rt) {
      u32 s1[4], s2[4];
#pragma unroll
      for (int ct = 0; ct < 4; ++ct) {
        u32 kb = kid0 + (u32)(ct * 16);
        u32 k0 = (__float_as_uint(acc[rt][ct][0]) & 0xFFFFFE00u) | kb;
        u32 k1 = (__float_as_uint(acc[rt][ct][1]) & 0xFFFFFE00u) | (kb + 1);
        u32 k2 = (__float_as_uint(acc[rt][ct][2]) & 0xFFFFFE00u) | (kb + 2);
        u32 k3 = (__float_as_uint(acc[rt][ct][3]) & 0xFFFFFE00u) | (kb + 3);
        u32 l0 = UMIN(k0, k1), h0 = UMAX(k0, k1);
        u32 l1 = UMIN(k2, k3), h1 = UMAX(k2, k3);
        s1[ct] = UMIN(l0, l1);
        s2[ct] = UMIN(UMAX(l0, l1), UMIN(h0, h1));
      }
      u32 a1_ = UMIN(s1[0], s1[1]);
      u32 a2_ = UMIN(UMAX(s1[0], s1[1]), UMIN(s2[0], s2[1]));
      u32 b1_ = UMIN(s1[2], s1[3]);
      u32 b2_ = UMIN(UMAX(s1[2], s1[3]), UMIN(s2[2], s2[3]));
      u32 m1 = UMIN(a1_, b1_);
      u32 m2 = UMIN(UMAX(a1_, b1_), UMIN(a2_, b2_));
      {
        u32 o1 = (u32)__shfl_xor((int)m1, 16);
        u32 o2 = (u32)__shfl_xor((int)m2, 16);
        u32 lo = UMIN(m1, o1), hi = UMAX(m1, o1), mn = UMIN(m2, o2);
        m1 = lo; m2 = UMIN(hi, mn);
      }
      {
        u32 o1 = (u32)__shfl_xor((int)m1, 32);
        u32 o2 = (u32)__shfl_xor((int)m2, 32);
        u32 lo = UMIN(m1, o1), hi = UMAX(m1, o1), mn = UMIN(m2, o2);
        m1 = lo; m2 = UMIN(hi, mn);
      }
      if (q == 0) {
        int r = rt * 16 + p;
        wsel[pb][r][w * 2] = m1;
        wsel[pb][r][w * 2 + 1] = m2;
      }
    }
#undef UMIN
#undef UMAX
  }
  __syncthreads();
  if (tid < 32) MERGE_EMIT(7, 1)
#undef ISSUE
#undef MERGE_EMIT
#undef ASHP
}

// ---------------------------------------------------------------------------
// Kernel 3 (BIG): finalize over 1024 cands/row (8 keys x 128 comp-cols).
__global__ __launch_bounds__(256)
void finalize_big(const float* __restrict__ x, const float* __restrict__ mean,
                  const float* __restrict__ stdd, const float* __restrict__ outs,
                  const u32* __restrict__ ckey, float* __restrict__ out) {
  __shared__ u32 cksh[1024];
  __shared__ float xr[256];
  __shared__ float part[256];
  __shared__ int selk[64];
  __shared__ float ew[32];
  __shared__ int kf[32];
  __shared__ float invs_sh;
  int tid = threadIdx.x, l = tid & 63, v = tid >> 6;
  int row = blockIdx.x;

  for (int i = tid; i < 1024; i += 256)
    cksh[i] = ckey[(size_t)row * 1024 + i];
  xr[tid] = x[(size_t)row * DDIM + tid];
  __syncthreads();

  {  // wave v: exact top-16 of its 256 cands
    u32 ext[4];
#pragma unroll
    for (int i = 0; i < 4; ++i) {
      int j = v * 256 + i * 64 + l;
      // 23-bit score | 8-bit position (l<<2 | i); 9-bit comp id dropped
      ext[i] = (cksh[j] & 0xFFFFFE00u) | ((u32)l << 2) | (u32)i;
    }
#define CSW(a, b) { if (ext[a] < ext[b]) { u32 t = ext[a]; ext[a] = ext[b]; ext[b] = t; } }
    CSW(0,1) CSW(2,3)
    CSW(0,2) CSW(1,3)
    CSW(1,2)
#undef CSW
    for (int it = 0; it < 16; ++it) {
      u32 m = ext[0];
      REDUCE_MAX(m)
      if (m == ext[0]) {
#pragma unroll
        for (int z = 0; z < 3; ++z) ext[z] = ext[z + 1];
        ext[3] = 0;
      }
      if (l == 0) {
        int wl = (int)((m >> 2) & 63u), wi = (int)(m & 3u);
        int j = v * 256 + wi * 64 + wl;
        // key j: comp-col j>>3 (512 comps), local id = low 9 bits inverted
        selk[v * 16 + it] = (int)((u32)(j >> 3) * 512u + (~cksh[j] & 0x1FFu));
      }
    }
  }
  __syncthreads();

  {  // exact fp32 lp for 64 cands, 4 threads each
    int j = tid >> 2, qq = tid & 3;
    int k = selk[j];
    const float* mr = mean + (size_t)k * DDIM + qq * 64;
    const float* sr = stdd + (size_t)k * DDIM + qq * 64;
    float s2 = 0.f, ls = 0.f;
    for (int i = 0; i < 16; ++i) {
      float4 m4 = *(const float4*)(mr + 4 * i);
      float4 s4 = *(const float4*)(sr + 4 * i);
      float4 x4 = *(const float4*)(&xr[qq * 64 + 4 * i]);
      { float is = __builtin_amdgcn_rcpf(s4.x); float df = (x4.x - m4.x) * is; s2 += df * df; ls += __logf(s4.x); }
      { float is = __builtin_amdgcn_rcpf(s4.y); float df = (x4.y - m4.y) * is; s2 += df * df; ls += __logf(s4.y); }
      { float is = __builtin_amdgcn_rcpf(s4.z); float df = (x4.z - m4.z) * is; s2 += df * df; ls += __logf(s4.z); }
      { float is = __builtin_amdgcn_rcpf(s4.w); float df = (x4.w - m4.w) * is; s2 += df * df; ls += __logf(s4.w); }
    }
    part[tid] = -0.5f * s2 - ls;
  }
  __syncthreads();

  if (tid < 64) {                      // exact top-32 + softmax (wave 0)
    float lp0 = part[l * 4] + part[l * 4 + 1] + part[l * 4 + 2] +
                part[l * 4 + 3] - LOG2PI_TERM;
    u32 ext = (fkey(lp0) & 0xFFFFFFC0u) | (u32)l;
    float maxlp = 0.f, ssum = 0.f;
    for (int it = 0; it < 32; ++it) {
      u32 m = ext;
      REDUCE_MAX(m)
      int j = (int)(m & 63u);
      u32 vb = m & 0xFFFFFFC0u;
      vb ^= (vb >> 31) ? 0x80000000u : 0xFFFFFFFFu;
      float lp = __uint_as_float(vb);
      if (it == 0) maxlp = lp;
      float e = __expf(lp - maxlp);
      ssum += e;
      if (l == 0) { ew[it] = e; kf[it] = selk[j]; }
      if (j == l) ext = 0;
    }
    if (l == 0) invs_sh = 1.0f / ssum;
  }
  __syncthreads();

  {  // weighted gather: one output element per thread
    float a = 0.f;
    for (int i = 0; i < 32; ++i)
      a += ew[i] * outs[(size_t)kf[i] * ODIM + tid];
    out[(size_t)row * ODIM + tid] = a * invs_sh;
  }
}

// ===========================================================================
// SMALL fallback path — r7 kernels verbatim (used when ws_size < ~69.3 MB).
// ===========================================================================
__global__ __launch_bounds__(512, 4)
void main_gemm_small(const u16* __restrict__ A_ws, const float* __restrict__ mean,
                     const float* __restrict__ stdd, u32* __restrict__ ckey) {
  __shared__ __align__(16) char lds_raw[66560];
  __shared__ u32 wsel[2][32][9];
  int tid = threadIdx.x, l = tid & 63, w = tid >> 6;
  int nb = blockIdx.x;
  int p = l & 15, q = l >> 4;
  int rt = w >> 2;
  int cg = w & 3;
  u32 kid0 = (u32)(cg * 16 + q * 4);

  bf16x8 wf[16];
  float myc0;
  f32x4 mycv;
  {
    u32* scr = (u32*)(lds_raw + w * 8320);
    int p8 = l & 7, q8 = l >> 3;
#pragma unroll
    for (int rr = 0; rr < 2; ++rr) {
      int comp = (nb * 4 + cg) * 16 + rr * 8 + p8;
      const float* mrow = mean + (size_t)comp * DDIM + q8 * 32;
      const float* srow = stdd + (size_t)comp * DDIM + q8 * 32;
      float gsum = 0.f;
#pragma unroll
      for (int i = 0; i < 8; ++i) {
        float4 m4 = *(const float4*)(mrow + 4 * i);
        float4 s4 = *(const float4*)(srow + 4 * i);
        float ms[4] = {m4.x, m4.y, m4.z, m4.w};
        float ss[4] = {s4.x, s4.y, s4.z, s4.w};
        u32 wd[4];
#pragma unroll
        for (int e = 0; e < 4; ++e) {
          float iv = __builtin_amdgcn_rcpf(ss[e] * ss[e]);
          float miv = ms[e] * iv;
          wd[e] = (u32)f2bf(-0.5f * iv) | ((u32)f2bf(-0.5f * miv) << 16);
          gsum -= 0.5f * ms[e] * miv + __logf(ss[e]);
        }
        uint4 v; v.x = wd[0]; v.y = wd[1]; v.z = wd[2]; v.w = wd[3];
        *(uint4*)(scr + p8 * 260 + q8 * 32 + i * 4) = v;
      }
      gsum += __shfl_xor(gsum, 8);
      gsum += __shfl_xor(gsum, 16);
      gsum += __shfl_xor(gsum, 32);
      if ((p >> 3) == rr) {
        myc0 = gsum - LOG2PI_TERM;
#pragma unroll
        for (int cc = 0; cc < 16; ++cc)
          wf[cc] = *(const bf16x8*)(scr + (p & 7) * 260 + cc * 16 + q * 4);
      }
    }
#pragma unroll
    for (int i = 0; i < 4; ++i)
      mycv[i] = __shfl(myc0, q * 4 + i);
  }
  __syncthreads();

#define ASHP(B, CELL) (lds_raw + ((size_t)(B) * 32 + (CELL)) * 1024)
#define ISSUE(S, B)                                                           \
  {                                                                           \
    _Pragma("unroll")                                                         \
    for (int u = 0; u < 4; ++u) {                                             \
      int cell = w * 4 + u;                                                   \
      const u16* gsrc = A_ws +                                                \
        ((size_t)((S) * 2 + (cell >> 4)) * 16 + (cell & 15)) * 512            \
        + (size_t)l * 8;                                                      \
      __builtin_amdgcn_global_load_lds((gconst_u32*)gsrc,                     \
          (lds_u32*)ASHP(B, cell), 16, 0, 0);                                 \
    }                                                                         \
  }
#define MERGE_EMIT(ST, B)                                                     \
  {                                                                           \
    int r = tid;                                                              \
    u32 b1 = ~0u, b2 = ~0u;                                                   \
    _Pragma("unroll")                                                         \
    for (int j = 0; j < 8; ++j) {                                             \
      u32 key = wsel[B][r][j];                                                \
      if (key < b1) { b2 = b1; b1 = key; }                                    \
      else if (key < b2) { b2 = key; }                                        \
    }                                                                         \
    int rowg = (ST) * 32 + r;                                                 \
    uint2 ov; ov.x = ~b1; ov.y = ~b2;                                         \
    *(uint2*)&ckey[((size_t)rowg * 1024 + nb) * 2] = ov;                      \
  }

  ISSUE(0, 0)
  for (int s = 0; s < 32; ++s) {
    int pb = s & 1;
    __syncthreads();
    if (s < 31) ISSUE(s + 1, pb ^ 1)
    if (s > 0 && tid < 32) MERGE_EMIT(s - 1, pb ^ 1)

    f32x4 aca = mycv;
    f32x4 acb = (f32x4){0.f, 0.f, 0.f, 0.f};
    __builtin_amdgcn_s_setprio(1);
#pragma unroll
    for (int cc = 0; cc < 8; ++cc) {
      bf16x8 a0 = *(const bf16x8*)(ASHP(pb, rt * 16 + cc) + (size_t)l * 16);
      bf16x8 a1 = *(const bf16x8*)(ASHP(pb, rt * 16 + 8 + cc) + (size_t)l * 16);
      aca = __builtin_amdgcn_mfma_f32_16x16x32_bf16(wf[cc], a0, aca, 0, 0, 0);
      acb = __builtin_amdgcn_mfma_f32_16x16x32_bf16(wf[8 + cc], a1, acb, 0, 0, 0);
    }
    __builtin_amdgcn_s_setprio(0);
    f32x4 ac;
    ac[0] = aca[0] + acb[0]; ac[1] = aca[1] + acb[1];
    ac[2] = aca[2] + acb[2]; ac[3] = aca[3] + acb[3];

#define UMIN(a, b) ((a) < (b) ? (a) : (b))
#define UMAX(a, b) ((a) < (b) ? (b) : (a))
    {
      u32 k0 = (__float_as_uint(ac[0]) & 0xFFFFFF00u) | (kid0 + 0);
      u32 k1 = (__float_as_uint(ac[1]) & 0xFFFFFF00u) | (kid0 + 1);
      u32 k2 = (__float_as_uint(ac[2]) & 0xFFFFFF00u) | (kid0 + 2);
      u32 k3 = (__float_as_uint(ac[3]) & 0xFFFFFF00u) | (kid0 + 3);
      u32 l0 = UMIN(k0, k1), h0 = UMAX(k0, k1);
      u32 l1 = UMIN(k2, k3), h1 = UMAX(k2, k3);
      u32 m1 = UMIN(l0, l1), m2 = UMIN(UMAX(l0, l1), UMIN(h0, h1));
      {
        u32 o1 = (u32)__shfl_xor((int)m1, 16);
        u32 o2 = (u32)__shfl_xor((int)m2, 16);
        u32 lo = UMIN(m1, o1), hi = UMAX(m1, o1), mn = UMIN(m2, o2);
        m1 = lo; m2 = UMIN(hi, mn);
      }
      {
        u32 o1 = (u32)__shfl_xor((int)m1, 32);
        u32 o2 = (u32)__shfl_xor((int)m2, 32);
        u32 lo = UMIN(m1, o1), hi = UMAX(m1, o1), mn = UMIN(m2, o2);
        m1 = lo; m2 = UMIN(hi, mn);
      }
      if (q == 0) {
        int r = rt * 16 + p;
        wsel[pb][r][cg * 2] = m1;
        wsel[pb][r][cg * 2 + 1] = m2;
      }
    }
#undef UMIN
#undef UMAX
  }
  __syncthreads();
  if (tid < 32) MERGE_EMIT(31, 1)
#undef ISSUE
#undef MERGE_EMIT
#undef ASHP
}

__global__ __launch_bounds__(256)
void finalize_small(const float* __restrict__ x, const float* __restrict__ mean,
                    const float* __restrict__ stdd, const float* __restrict__ outs,
                    const u32* __restrict__ ckey, float* __restrict__ out) {
  __shared__ u32 cksh[2048];
  __shared__ float xr[256];
  __shared__ float part[256];
  __shared__ int selk[64];
  __shared__ float ew[32];
  __shared__ int kf[32];
  __shared__ float invs_sh;
  int tid = threadIdx.x, l = tid & 63, v = tid >> 6;
  int row = blockIdx.x;

  for (int i = tid; i < 2048; i += 256)
    cksh[i] = ckey[(size_t)row * 2048 + i];
  xr[tid] = x[(size_t)row * DDIM + tid];
  __syncthreads();

  {
    u32 ext[8];
#pragma unroll
    for (int i = 0; i < 8; ++i) {
      int j = v * 512 + i * 64 + l;
      ext[i] = (cksh[j] & 0xFFFFFE00u) | ((u32)l << 3) | (u32)i;
    }
#define CSW(a, b) { if (ext[a] < ext[b]) { u32 t = ext[a]; ext[a] = ext[b]; ext[b] = t; } }
    CSW(0,1) CSW(2,3) CSW(4,5) CSW(6,7)
    CSW(0,2) CSW(1,3) CSW(4,6) CSW(5,7)
    CSW(1,2) CSW(5,6)
    CSW(0,4) CSW(1,5) CSW(2,6) CSW(3,7)
    CSW(2,4) CSW(3,5)
    CSW(1,2) CSW(3,4) CSW(5,6)
#undef CSW
    for (int it = 0; it < 16; ++it) {
      u32 m = ext[0];
      REDUCE_MAX(m)
      if (m == ext[0]) {
#pragma unroll
        for (int z = 0; z < 7; ++z) ext[z] = ext[z + 1];
        ext[7] = 0;
      }
      if (l == 0) {
        int wl = (int)((m >> 3) & 63u), wi = (int)(m & 7u);
        int j = v * 512 + wi * 64 + wl;
        selk[v * 16 + it] = (int)((u32)(j >> 1) * 64u + (~cksh[j] & 0x3Fu));
      }
    }
  }
  __syncthreads();

  {
    int j = tid >> 2, qq = tid & 3;
    int k = selk[j];
    const float* mr = mean + (size_t)k * DDIM + qq * 64;
    const float* sr = stdd + (size_t)k * DDIM + qq * 64;
    float s2 = 0.f, ls = 0.f;
    for (int i = 0; i < 16; ++i) {
      float4 m4 = *(const float4*)(mr + 4 * i);
      float4 s4 = *(const float4*)(sr + 4 * i);
      float4 x4 = *(const float4*)(&xr[qq * 64 + 4 * i]);
      { float is = __builtin_amdgcn_rcpf(s4.x); float df = (x4.x - m4.x) * is; s2 += df * df; ls += __logf(s4.x); }
      { float is = __builtin_amdgcn_rcpf(s4.y); float df = (x4.y - m4.y) * is; s2 += df * df; ls += __logf(s4.y); }
      { float is = __builtin_amdgcn_rcpf(s4.z); float df = (x4.z - m4.z) * is; s2 += df * df; ls += __logf(s4.z); }
      { float is = __builtin_amdgcn_rcpf(s4.w); float df = (x4.w - m4.w) * is; s2 += df * df; ls += __logf(s4.w); }
    }
    part[tid] = -0.5f * s2 - ls;
  }
  __syncthreads();

  if (tid < 64) {
    float lp0 = part[l * 4] + part[l * 4 + 1] + part[l * 4 + 2] +
                part[l * 4 + 3] - LOG2PI_TERM;
    u32 ext = (fkey(lp0) & 0xFFFFFFC0u) | (u32)l;
    float maxlp = 0.f, ssum = 0.f;
    for (int it = 0; it < 32; ++it) {
      u32 m = ext;
      REDUCE_MAX(m)
      int j = (int)(m & 63u);
      u32 vb = m & 0xFFFFFFC0u;
      vb ^= (vb >> 31) ? 0x80000000u : 0xFFFFFFFFu;
      float lp = __uint_as_float(vb);
      if (it == 0) maxlp = lp;
      float e = __expf(lp - maxlp);
      ssum += e;
      if (l == 0) { ew[it] = e; kf[it] = selk[j]; }
      if (j == l) ext = 0;
    }
    if (l == 0) invs_sh = 1.0f / ssum;
  }
  __syncthreads();

  {
    float a = 0.f;
    for (int i = 0; i < 32; ++i)
      a += ew[i] * outs[(size_t)kf[i] * ODIM + tid];
    out[(size_t)row * ODIM + tid] = a * invs_sh;
  }
}

// ---------------------------------------------------------------------------
extern "C" void kernel_launch(void* const* d_in, const int* in_sizes, int n_in,
                              void* d_out, int out_size, void* d_ws, size_t ws_size,
                              hipStream_t stream) {
  const float* x = (const float*)d_in[0];
  const float* mean = (const float*)d_in[1];
  const float* stdd = (const float*)d_in[2];
  const float* outs = (const float*)d_in[3];
  char* ws = (char*)d_ws;
  u16* A_ws = (u16*)(ws + WS_A);

  if (ws_size >= WS_NEED_BIG) {
    u16* W_ws = (u16*)(ws + WS_W);
    float* myc_ws = (float*)(ws + WS_MYC);
    u32* ckey = (u32*)(ws + WS_KEYB);
    prep_A<<<64, 256, 0, stream>>>(x, A_ws);
    prep_W<<<4096, 256, 0, stream>>>(mean, stdd, W_ws, myc_ws);
    main_gemm_big<<<512, 512, 0, stream>>>(A_ws, W_ws, myc_ws, ckey);
    finalize_big<<<BROWS, 256, 0, stream>>>(x, mean, stdd, outs, ckey,
                                            (float*)d_out);
  } else {
    u32* ckey = (u32*)(ws + WS_KEYS);
    prep_A<<<64, 256, 0, stream>>>(x, A_ws);
    main_gemm_small<<<1024, 512, 0, stream>>>(A_ws, mean, stdd, ckey);
    finalize_small<<<BROWS, 256, 0, stream>>>(x, mean, stdd, outs, ckey,
                                              (float*)d_out);
  }
}